// Round 6
// baseline (297.002 us; speedup 1.0000x reference)
//
#include <hip/hip_runtime.h>
#include <math.h>

// ---------------------------------------------------------------------------
// SingleHeadSelfAttention: B=4, S=2048, C=2048, d=512
// R12: R11 with launch_bounds reverted to (512,2). R11's (512,4) forced the
//      unified VGPR/AGPR budget to 128/wave < live set (acc 128 + frags 48)
//      -> scratch spill in the K-loop -> timeout. The 2-wg/CU occupancy is
//      achieved by the LDS halving alone: 2-slot ring = 64 KiB/wg, and at
//      the compiler's natural VGPR=128 the HW already permits 4 waves/SIMD.
//      - gemm256: 2-slot LDS ring, counted vmcnt(4) across barriers; the
//        2nd resident wg supplies the LDS<->MFMA pipe overlap (m97/m114).
//      - score: R7-proven EPI4 (S^T; packed C^T store = expS[q][k] row-major;
//        col-sum atomics -> rsum[q]).
//      - pv: A=expS[q][k], B=vT on the BN=64 old core -> 512 wgs (2 wg/CU),
//        /rsum[row], row-major coalesced ctx stores.
// ---------------------------------------------------------------------------

typedef __bf16 bf16;
typedef bf16 bf16x8 __attribute__((ext_vector_type(8)));
typedef bf16 bf16x4 __attribute__((ext_vector_type(4)));
typedef float f32x4 __attribute__((ext_vector_type(4)));

#define BB 4
#define SS 2048
#define CC 2048
#define DD 512
#define ND3 1536          // 3*DD
#define MM 8192           // BB*SS

typedef const __attribute__((address_space(1))) unsigned int g_u32;
typedef __attribute__((address_space(3))) unsigned int l_u32;

__device__ __forceinline__ void gl_lds16(const bf16* g, bf16* l) {
    __builtin_amdgcn_global_load_lds((g_u32*)g, (l_u32*)l, 16, 0, 0);
}

#define VMW(n) asm volatile("s_waitcnt vmcnt(" #n ")" ::: "memory")
#define LKW0   asm volatile("s_waitcnt lgkmcnt(0)" ::: "memory")
#define BAR    __builtin_amdgcn_s_barrier()

// ---------------- prep: fp32->bf16 for x/Wqkv/Wo + zero rsum ---------------
#define N4_X   (MM * CC / 4)          // 4194304
#define N4_WQ  (ND3 * CC / 4)         //  786432
#define N4_WO  (CC * DD / 4)          //  262144
#define N4_RS  (MM / 4)               //    2048
#define N4_TOT (N4_X + N4_WQ + N4_WO + N4_RS)

__global__ __launch_bounds__(256) void prep(const float* __restrict__ x,
                                            const float* __restrict__ Wqkv,
                                            const float* __restrict__ Wo,
                                            bf16* __restrict__ xb,
                                            bf16* __restrict__ wqkvb,
                                            bf16* __restrict__ wob,
                                            float* __restrict__ rsum) {
    int i = blockIdx.x * 256 + threadIdx.x;
    const int stride = gridDim.x * 256;
    for (; i < N4_TOT; i += stride) {
        if (i < N4_X + N4_WQ + N4_WO) {
            const float* src; bf16* dst; int j = i;
            if (j < N4_X)                { src = x;    dst = xb; }
            else if (j < N4_X + N4_WQ)   { src = Wqkv; dst = wqkvb; j -= N4_X; }
            else                         { src = Wo;   dst = wob;   j -= N4_X + N4_WQ; }
            float4 v = ((const float4*)src)[j];
            bf16x4 o;
            o[0] = (bf16)v.x; o[1] = (bf16)v.y; o[2] = (bf16)v.z; o[3] = (bf16)v.w;
            ((bf16x4*)dst)[j] = o;
        } else {
            int j = i - (N4_X + N4_WQ + N4_WO);
            ((float4*)rsum)[j] = float4{0.f, 0.f, 0.f, 0.f};
        }
    }
}

// ---------------------------------------------------------------------------
// 256x256 tile core, 8 waves (2Mx4N), per-wave 128x64 (acc[8][4]).
// K in 32-col chunks through a 2-slot LDS ring (64 KiB dynamic -> 2 wgs/CU).
// Chunk j: FRAGS(j) [12 ds_read slot j&1] -> 32 MFMA -> lgkm(0)+barrier
//   [all reads of slot j&1 retired] -> STAGE(j+2) into slot j&1 ->
//   vmcnt(4)+barrier [chunk j+1 landed for every wave; j+2 stays in flight].
// Tail: at NC-2 use vmcnt(0) (only NC-1's 4 loads outstanding).
// Swizzle: both-sides XOR involution; LDS dest linear (global_load_lds req).
// EPI: 0 = scale*acc + bias[col], row-major fp32 stores (k_out)
//      3 = QKV split: col<1024 row-major bf16; col>=1024 transposed into vT
//      4 = scoresT: exp(scale*acc), packed b64 C^T store (= expS[q][k]
//          row-major), col-sum shuffle-reduce + atomics into rsum[q]
// ---------------------------------------------------------------------------
#define SLOT_E 16384
#define CH_B   8192

template <bool OUT_BF16, int EPI>
__device__ __forceinline__ void gemm256_body(const bf16* __restrict__ A,
                                             const bf16* __restrict__ Bm,
                                             const float* __restrict__ bias,
                                             float* __restrict__ rowsum,
                                             bf16* __restrict__ vTp,
                                             void* __restrict__ Cv,
                                             int K, int lda, int ldb, int ldc,
                                             long ab, long bb, long cb,
                                             float scale) {
    extern __shared__ bf16 lds[];
    A  += (size_t)blockIdx.z * ab;
    Bm += (size_t)blockIdx.z * bb;
    const int m0 = blockIdx.y * 256, n0 = blockIdx.x * 256;
    const int t = threadIdx.x, lane = t & 63, w = t >> 6;
    const int wm = (w >> 2) * 128, wn = (w & 3) * 64;
    const int cl = lane & 15, q = lane >> 4;
    const int swzr = (q ^ ((cl >> 1) & 3)) * 8;        // read-side XOR swizzle
    const int srow = t >> 2;
    const int swz  = (t & 3) ^ ((t >> 3) & 3);
    const bf16* pa = A  + (size_t)(m0 + srow) * lda + swz * 8;
    const bf16* pb = Bm + (size_t)(n0 + srow) * ldb + swz * 8;
    bf16* lw = lds + w * 512;                          // wave-uniform LDS base

    f32x4 acc[8][4] = {};
    const int NC = K >> 5;                             // K/32 chunks (>= 3)

    auto STAGE = [&](int j) {
        bf16* s = lw + (j & 1) * SLOT_E;
        const bf16* ga = pa + j * 32;
        const bf16* gb = pb + j * 32;
        gl_lds16(ga,                     s);
        gl_lds16(ga + (size_t)128 * lda, s + 4096);
        gl_lds16(gb,                     s + CH_B);
        gl_lds16(gb + (size_t)128 * ldb, s + CH_B + 4096);
    };
    auto FRAGS = [&](int j, bf16x8 (&af)[8], bf16x8 (&bfr)[4]) {
        const bf16* sa = lds + (j & 1) * SLOT_E + (wm + cl) * 32 + swzr;
        const bf16* sb = lds + (j & 1) * SLOT_E + CH_B + (wn + cl) * 32 + swzr;
#pragma unroll
        for (int i = 0; i < 8; i++)  af[i]  = *(const bf16x8*)(sa + i * 512);
#pragma unroll
        for (int jj = 0; jj < 4; jj++) bfr[jj] = *(const bf16x8*)(sb + jj * 512);
    };
    auto MFMAS = [&](bf16x8 (&af)[8], bf16x8 (&bfr)[4]) {
        __builtin_amdgcn_s_setprio(1);
#pragma unroll
        for (int i = 0; i < 8; i++)
#pragma unroll
            for (int jj = 0; jj < 4; jj++)
                acc[i][jj] = __builtin_amdgcn_mfma_f32_16x16x32_bf16(
                                 af[i], bfr[jj], acc[i][jj], 0, 0, 0);
        __builtin_amdgcn_s_setprio(0);
    };

    STAGE(0); STAGE(1);
    VMW(4); BAR;                       // chunk 0 landed; chunk 1 in flight

    for (int j = 0; j < NC - 2; ++j) {
        bf16x8 af[8], bfr[4];
        FRAGS(j, af, bfr);
        MFMAS(af, bfr);
        LKW0; BAR;                     // all reads of slot j&1 retired
        STAGE(j + 2);                  // overwrite slot j&1
        VMW(4); BAR;                   // chunk j+1 landed everywhere
    }
    {   bf16x8 af[8], bfr[4];
        FRAGS(NC - 2, af, bfr); MFMAS(af, bfr);
        VMW(0); BAR;                   // chunk NC-1 landed
    }
    {   bf16x8 af[8], bfr[4];
        FRAGS(NC - 1, af, bfr); MFMAS(af, bfr);
    }

    if constexpr (EPI == 4) {          // scoresT: exp, packed C^T, col-sums
        float cs[4] = {0.f, 0.f, 0.f, 0.f};
#pragma unroll
        for (int i = 0; i < 8; i++)
#pragma unroll
            for (int jj = 0; jj < 4; jj++) {
                int col = n0 + wn + jj * 16 + cl;
                int row = m0 + wm + i * 16 + q * 4;
                bf16x4 o;
#pragma unroll
                for (int r = 0; r < 4; r++) {
                    float e = __expf(acc[i][jj][r] * scale);
                    cs[jj] += e;
                    o[r] = (bf16)e;
                }
                *(bf16x4*)&((bf16*)Cv)[(size_t)blockIdx.z * cb + (size_t)col * ldc + row] = o;
            }
#pragma unroll
        for (int jj = 0; jj < 4; jj++) {
            cs[jj] += __shfl_xor(cs[jj], 16, 64);
            cs[jj] += __shfl_xor(cs[jj], 32, 64);
        }
        if (q == 0) {
#pragma unroll
            for (int jj = 0; jj < 4; jj++)
                atomicAdd(&rowsum[(size_t)blockIdx.z * SS + n0 + wn + jj * 16 + cl], cs[jj]);
        }
        return;
    }

    const bool v_block = (EPI == 3) && (n0 >= 1024);
#pragma unroll
    for (int i = 0; i < 8; i++) {
#pragma unroll
        for (int jj = 0; jj < 4; jj++) {
            int col = n0 + wn + jj * 16 + cl;
            float bvv = bias ? bias[col] : 0.0f;
            if (v_block) {
                int row = m0 + wm + i * 16 + q * 4;
                int b = row >> 11, s = row & 2047;
                bf16x4 o;
#pragma unroll
                for (int r = 0; r < 4; r++) o[r] = (bf16)(acc[i][jj][r] * scale + bvv);
                *(bf16x4*)&vTp[((size_t)b * DD + (col - 1024)) * SS + s] = o;
            } else {
#pragma unroll
                for (int r = 0; r < 4; r++) {
                    int row = m0 + wm + i * 16 + q * 4 + r;
                    float val = acc[i][jj][r] * scale + bvv;
                    if (OUT_BF16)
                        ((bf16*)Cv)[(size_t)blockIdx.z * cb + (size_t)row * ldc + col] = (bf16)val;
                    else
                        ((float*)Cv)[(size_t)blockIdx.z * cb + (size_t)row * ldc + col] = val;
                }
            }
        }
    }
}

// ---------------------------------------------------------------------------
// k_pv: 128x64 tiles on the old 2-barrier core. A=expS[q][k] (lda=SS),
// B=vT[d][s] (ldb=SS), C=ctx[q][d] row-major (ldc=DD), /rsum[row].
// Grid (DD/64, SS/128, BB) = 512 wgs -> 2 wg/CU, cross-wg overlap.
// ---------------------------------------------------------------------------
__global__ __launch_bounds__(256) void k_pv(const bf16* __restrict__ A,
        const bf16* __restrict__ Bm, float* __restrict__ rowsum,
        bf16* __restrict__ Cv, int K, int lda, int ldb, int ldc,
        long ab, long bb, long cb) {
    __shared__ bf16 As[128 * 64];
    __shared__ bf16 Bs[64 * 64];
    A += (size_t)blockIdx.z * ab;
    Bm += (size_t)blockIdx.z * bb;
    const int m0 = blockIdx.y * 128, n0 = blockIdx.x * 64;
    const int t = threadIdx.x, lane = t & 63, w = t >> 6;
    const int wm = w * 32;             // 4 waves stacked in M, full N per wave
    const int q = lane >> 4, cl = lane & 15;
    const int srow = lane >> 3;
    const int sblk = (lane & 7) ^ srow;
    const int scol = sblk * 8;
    const bf16* pa = A + (size_t)(m0 + w * 32 + srow) * lda + scol;
    const bf16* pb = Bm + (size_t)(n0 + w * 16 + srow) * ldb + scol;
    bf16* lA = As + (w * 32) * 64;
    bf16* lB = Bs + (w * 16) * 64;
    const int rblk0 = (q ^ (cl & 7)) * 8;
    const int rblk1 = ((4 + q) ^ (cl & 7)) * 8;

    f32x4 acc[2][4] = {};
    for (int k0 = 0; k0 < K; k0 += 64) {
#pragma unroll
        for (int n = 0; n < 4; n++)
            gl_lds16(pa + k0 + (size_t)(n * 8) * lda, lA + n * 8 * 64);
#pragma unroll
        for (int n = 0; n < 2; n++)
            gl_lds16(pb + k0 + (size_t)(n * 8) * ldb, lB + n * 8 * 64);
        __syncthreads();
#pragma unroll
        for (int h = 0; h < 2; h++) {
            const int rb = h ? rblk1 : rblk0;
            bf16x8 af[2], bfr[4];
#pragma unroll
            for (int i = 0; i < 2; i++)
                af[i] = *(const bf16x8*)&As[(wm + i * 16 + cl) * 64 + rb];
#pragma unroll
            for (int j = 0; j < 4; j++)
                bfr[j] = *(const bf16x8*)&Bs[(j * 16 + cl) * 64 + rb];
#pragma unroll
            for (int i = 0; i < 2; i++)
#pragma unroll
                for (int j = 0; j < 4; j++)
                    acc[i][j] = __builtin_amdgcn_mfma_f32_16x16x32_bf16(af[i], bfr[j], acc[i][j], 0, 0, 0);
        }
        __syncthreads();
    }

    // divide by rowsum[row] (row = q index), store ctx[row][col] row-major
    float inv[2][4];
#pragma unroll
    for (int i = 0; i < 2; i++)
#pragma unroll
        for (int r = 0; r < 4; r++)
            inv[i][r] = 1.0f / rowsum[(size_t)blockIdx.z * SS + m0 + wm + i * 16 + q * 4 + r];
#pragma unroll
    for (int i = 0; i < 2; i++)
#pragma unroll
        for (int j = 0; j < 4; j++) {
            int col = n0 + j * 16 + cl;
#pragma unroll
            for (int r = 0; r < 4; r++) {
                int row = m0 + wm + i * 16 + q * 4 + r;
                Cv[(size_t)blockIdx.z * cb + (size_t)row * ldc + col] =
                    (bf16)(acc[i][j][r] * inv[i][r]);
            }
        }
}

// distinct names so rocprof reports per-role counters
__global__ __launch_bounds__(512, 2) void k_qkv(const bf16* A, const bf16* Bm,
        const float* bias, bf16* vTp, void* Cv, int K, int lda, int ldb, int ldc,
        float scale) {
    gemm256_body<true, 3>(A, Bm, bias, nullptr, vTp, Cv, K, lda, ldb, ldc, 0, 0, 0, scale);
}
__global__ __launch_bounds__(512, 2) void k_score(const bf16* A, const bf16* Bm,
        float* rowsum, void* Cv, int K, int lda, int ldb, int ldc,
        long ab, long bb, long cb, float scale) {
    gemm256_body<true, 4>(A, Bm, nullptr, rowsum, nullptr, Cv, K, lda, ldb, ldc, ab, bb, cb, scale);
}
__global__ __launch_bounds__(512, 2) void k_out(const bf16* A, const bf16* Bm,
        const float* bias, void* Cv, int K, int lda, int ldb, int ldc,
        float scale) {
    gemm256_body<false, 0>(A, Bm, bias, nullptr, nullptr, Cv, K, lda, ldb, ldc, 0, 0, 0, scale);
}

// ---------------------------------------------------------------------------
extern "C" void kernel_launch(void* const* d_in, const int* in_sizes, int n_in,
                              void* d_out, int out_size, void* d_ws, size_t ws_size,
                              hipStream_t stream) {
    const float* x    = (const float*)d_in[0];  // (4,2048,2048)
    const float* Wqkv = (const float*)d_in[1];  // (1536,2048)
    const float* bqkv = (const float*)d_in[2];  // (1536,)
    const float* Wo   = (const float*)d_in[3];  // (2048,512)
    const float* bo   = (const float*)d_in[4];  // (2048,)
    float* out = (float*)d_out;                 // (4,2048,2048) fp32

    char* ws = (char*)d_ws;
    size_t off = 0;
    bf16* xb    = (bf16*)(ws + off); off += (size_t)MM * CC * 2;       // 32 MB
    bf16* wqkvb = (bf16*)(ws + off); off += (size_t)ND3 * CC * 2;      // 6 MB
    bf16* wob   = (bf16*)(ws + off); off += (size_t)CC * DD * 2;       // 2 MB
    bf16* qkvb  = (bf16*)(ws + off); off += (size_t)MM * ND3 * 2;      // 24 MB
    bf16* vT    = (bf16*)(ws + off); off += (size_t)BB * DD * SS * 2;  // 8 MB
    bf16* expS  = (bf16*)(ws + off); off += (size_t)BB * SS * SS * 2;  // 32 MB
    bf16* ctxb  = (bf16*)(ws + off); off += (size_t)MM * DD * 2;       // 8 MB
    float* rsum = (float*)(ws + off); off += (size_t)MM * 4;           // 32 KB

    // allow 64 KiB dynamic LDS on the 2-slot ring kernels
    static int lds_attr_set = 0;
    if (!lds_attr_set) {
        hipFuncSetAttribute((const void*)k_qkv,
                            hipFuncAttributeMaxDynamicSharedMemorySize, 65536);
        hipFuncSetAttribute((const void*)k_score,
                            hipFuncAttributeMaxDynamicSharedMemorySize, 65536);
        hipFuncSetAttribute((const void*)k_out,
                            hipFuncAttributeMaxDynamicSharedMemorySize, 65536);
        lds_attr_set = 1;
    }

    // 1. convert inputs to bf16 + zero rsum
    prep<<<2048, 256, 0, stream>>>(x, Wqkv, Wo, xb, wqkvb, wob, rsum);

    // 2. qkv = x Wqkv^T + bqkv; q,k -> qkvb rows, v -> vT transposed
    k_qkv<<<dim3(ND3 / 256, MM / 256, 1), 512, 65536, stream>>>(
        xb, wqkvb, bqkv, vT, qkvb, CC, CC, CC, ND3, 1.0f);

    // 3. expS = exp(q k^T / sqrt(d)) via S^T = k q^T; packed C^T store gives
    //    expS[q][k] row-major; col-sum atomics -> rsum[q]
    k_score<<<dim3(SS / 256, SS / 256, BB), 512, 65536, stream>>>(
        qkvb + 512 /*k*/, qkvb /*q*/, rsum, expS,
        DD, ND3, ND3, SS,
        (long)SS * ND3, (long)SS * ND3, (long)SS * SS,
        0.044194173824159216f /* 1/sqrt(512) */);

    // 4. ctx[q][d] = (expS x vT^T)/rsum[q]; row-major stores
    k_pv<<<dim3(DD / 64, SS / 128, BB), 256, 0, stream>>>(
        expS, vT, rsum, ctxb,
        SS, SS, SS, DD,
        (long)SS * SS, (long)DD * SS, (long)SS * DD);

    // 5. out = ctx Wo^T + bo  (M=8192, N=2048, K=512) -> fp32
    k_out<<<dim3(CC / 256, MM / 256, 1), 512, 65536, stream>>>(
        ctxb, wob, bo, out, DD, DD, DD, CC, 1.0f);

    (void)in_sizes; (void)n_in; (void)out_size; (void)ws_size;
}

// Round 7
// 273.361 us; speedup vs baseline: 1.0865x; 1.0865x over previous
//
#include <hip/hip_runtime.h>
#include <math.h>

// ---------------------------------------------------------------------------
// SingleHeadSelfAttention: B=4, S=2048, C=2048, d=512
// R13: full revert to R7 (best measured per-kernel: 4-slot ring monophase
//      for qkv/score/out, old BN=64 C^T core for pv) + XCD-aware block
//      swizzle (T1) on all four GEMMs. Schedule variants R8/R9/R11/R12 all
//      regressed vs R7's monophase -> R7 structure is the local optimum at
//      1 wg/CU. Swizzle rationale: consecutive dispatch indices round-robin
//      XCDs while walking the N-dim (same A-panel) -> A-panels fetched into
//      up to 6 different per-XCD L2s (FETCH 111MB vs 38MB unique on qkv).
//      s = (d%8)*(nwg/8) + d/8 gives each XCD a contiguous work range
//      (bijective: nwg%8==0 for all grids: 192/256/512/256).
// ---------------------------------------------------------------------------

typedef __bf16 bf16;
typedef bf16 bf16x8 __attribute__((ext_vector_type(8)));
typedef bf16 bf16x4 __attribute__((ext_vector_type(4)));
typedef float f32x4 __attribute__((ext_vector_type(4)));

#define BB 4
#define SS 2048
#define CC 2048
#define DD 512
#define ND3 1536          // 3*DD
#define MM 8192           // BB*SS

typedef const __attribute__((address_space(1))) unsigned int g_u32;
typedef __attribute__((address_space(3))) unsigned int l_u32;

__device__ __forceinline__ void gl_lds16(const bf16* g, bf16* l) {
    __builtin_amdgcn_global_load_lds((g_u32*)g, (l_u32*)l, 16, 0, 0);
}

#define VMW(n) asm volatile("s_waitcnt vmcnt(" #n ")" ::: "memory")
#define BAR    __builtin_amdgcn_s_barrier()

// XCD-aware swizzle: dispatch slot d runs on XCD d%8; remap so XCD k gets a
// CONTIGUOUS work range [k*nwg/8, (k+1)*nwg/8). Requires nwg % 8 == 0.
__device__ __forceinline__ void xcd_swz(int& bx, int& by, int& bz) {
    const int gx = gridDim.x, gy = gridDim.y;
    const int nwg = gx * gy * gridDim.z;
    const int d = (blockIdx.z * gy + blockIdx.y) * gx + blockIdx.x;
    const int s = (d & 7) * (nwg >> 3) + (d >> 3);
    bx = s % gx;
    const int t2 = s / gx;
    by = t2 % gy;
    bz = t2 / gy;
}

// ---------------- prep: fp32->bf16 for x/Wqkv/Wo + zero rsum ---------------
#define N4_X   (MM * CC / 4)          // 4194304
#define N4_WQ  (ND3 * CC / 4)         //  786432
#define N4_WO  (CC * DD / 4)          //  262144
#define N4_RS  (MM / 4)               //    2048
#define N4_TOT (N4_X + N4_WQ + N4_WO + N4_RS)

__global__ __launch_bounds__(256) void prep(const float* __restrict__ x,
                                            const float* __restrict__ Wqkv,
                                            const float* __restrict__ Wo,
                                            bf16* __restrict__ xb,
                                            bf16* __restrict__ wqkvb,
                                            bf16* __restrict__ wob,
                                            float* __restrict__ rsum) {
    int i = blockIdx.x * 256 + threadIdx.x;
    const int stride = gridDim.x * 256;
    for (; i < N4_TOT; i += stride) {
        if (i < N4_X + N4_WQ + N4_WO) {
            const float* src; bf16* dst; int j = i;
            if (j < N4_X)                { src = x;    dst = xb; }
            else if (j < N4_X + N4_WQ)   { src = Wqkv; dst = wqkvb; j -= N4_X; }
            else                         { src = Wo;   dst = wob;   j -= N4_X + N4_WQ; }
            float4 v = ((const float4*)src)[j];
            bf16x4 o;
            o[0] = (bf16)v.x; o[1] = (bf16)v.y; o[2] = (bf16)v.z; o[3] = (bf16)v.w;
            ((bf16x4*)dst)[j] = o;
        } else {
            int j = i - (N4_X + N4_WQ + N4_WO);
            ((float4*)rsum)[j] = float4{0.f, 0.f, 0.f, 0.f};
        }
    }
}

// ---------------------------------------------------------------------------
// 256x256 monophase ring core (R7, verified best). 8 waves (2Mx4N), per-wave
// 128x64 output (acc[8][4]). K in 32-col chunks, 4-slot LDS ring (128 KiB).
// Chunk j: 12 ds_read | STAGE(j+3) (4 gl_lds) | 32 MFMA | vmcnt(8) | barrier.
// vmcnt(8) leaves chunks j+2,j+3 in flight => chunk j+1 landed for next
// chunk; slot overwrite safe (readers of slot (j-1)&3 drained at barrier).
// Swizzle: both-sides XOR involution; LDS dest linear (global_load_lds req).
// EPI: 0 = scale*acc + bias[col], row-major fp32 stores (k_out)
//      3 = QKV split: col<1024 row-major bf16; col>=1024 transposed into vT
//      4 = scoresT: exp(scale*acc), packed b64 C^T store (= expS[q][k]
//          row-major), col-sum shuffle-reduce + atomics into rsum[q]
// ---------------------------------------------------------------------------
#define SLOT_E 16384
#define CH_B   8192

template <bool OUT_BF16, int EPI>
__device__ __forceinline__ void gemm256_body(const bf16* __restrict__ A,
                                             const bf16* __restrict__ Bm,
                                             const float* __restrict__ bias,
                                             float* __restrict__ rowsum,
                                             bf16* __restrict__ vTp,
                                             void* __restrict__ Cv,
                                             int K, int lda, int ldb, int ldc,
                                             long ab, long bb, long cb,
                                             float scale) {
    extern __shared__ bf16 lds[];
    int bx, by, bz;
    xcd_swz(bx, by, bz);
    A  += (size_t)bz * ab;
    Bm += (size_t)bz * bb;
    const int m0 = by * 256, n0 = bx * 256;
    const int t = threadIdx.x, lane = t & 63, w = t >> 6;
    const int wm = (w >> 2) * 128, wn = (w & 3) * 64;
    const int cl = lane & 15, q = lane >> 4;
    const int swzr = (q ^ ((cl >> 1) & 3)) * 8;        // read-side XOR swizzle
    const int srow = t >> 2;
    const int swz  = (t & 3) ^ ((t >> 3) & 3);
    const bf16* pa = A  + (size_t)(m0 + srow) * lda + swz * 8;
    const bf16* pb = Bm + (size_t)(n0 + srow) * ldb + swz * 8;
    bf16* lw = lds + w * 512;                          // wave-uniform LDS base

    f32x4 acc[8][4] = {};
    const int NC = K >> 5;                             // K/32 chunks (>= 4)

    auto STAGE = [&](int j) {
        bf16* s = lw + (j & 3) * SLOT_E;
        const bf16* ga = pa + j * 32;
        const bf16* gb = pb + j * 32;
        gl_lds16(ga,                     s);
        gl_lds16(ga + (size_t)128 * lda, s + 4096);
        gl_lds16(gb,                     s + CH_B);
        gl_lds16(gb + (size_t)128 * ldb, s + CH_B + 4096);
    };
    auto FRAGS = [&](int j, bf16x8 (&af)[8], bf16x8 (&bfr)[4]) {
        const bf16* sa = lds + (j & 3) * SLOT_E + (wm + cl) * 32 + swzr;
        const bf16* sb = lds + (j & 3) * SLOT_E + CH_B + (wn + cl) * 32 + swzr;
#pragma unroll
        for (int i = 0; i < 8; i++)  af[i]  = *(const bf16x8*)(sa + i * 512);
#pragma unroll
        for (int jj = 0; jj < 4; jj++) bfr[jj] = *(const bf16x8*)(sb + jj * 512);
    };
    auto MFMAS = [&](bf16x8 (&af)[8], bf16x8 (&bfr)[4]) {
        __builtin_amdgcn_s_setprio(1);
#pragma unroll
        for (int i = 0; i < 8; i++)
#pragma unroll
            for (int jj = 0; jj < 4; jj++)
                acc[i][jj] = __builtin_amdgcn_mfma_f32_16x16x32_bf16(
                                 af[i], bfr[jj], acc[i][jj], 0, 0, 0);
        __builtin_amdgcn_s_setprio(0);
    };

    STAGE(0); STAGE(1); STAGE(2);
    VMW(8); BAR;

    for (int j = 0; j < NC - 3; ++j) {
        bf16x8 af[8], bfr[4];
        FRAGS(j, af, bfr);
        STAGE(j + 3);
        MFMAS(af, bfr);
        VMW(8); BAR;
    }
    {   bf16x8 af[8], bfr[4];
        FRAGS(NC - 3, af, bfr); MFMAS(af, bfr);
        VMW(4); BAR;
    }
    {   bf16x8 af[8], bfr[4];
        FRAGS(NC - 2, af, bfr); MFMAS(af, bfr);
        VMW(0); BAR;
    }
    {   bf16x8 af[8], bfr[4];
        FRAGS(NC - 1, af, bfr); MFMAS(af, bfr);
    }

    if constexpr (EPI == 4) {          // scoresT: exp, packed C^T, col-sums
        float cs[4] = {0.f, 0.f, 0.f, 0.f};
#pragma unroll
        for (int i = 0; i < 8; i++)
#pragma unroll
            for (int jj = 0; jj < 4; jj++) {
                int col = n0 + wn + jj * 16 + cl;
                int row = m0 + wm + i * 16 + q * 4;
                bf16x4 o;
#pragma unroll
                for (int r = 0; r < 4; r++) {
                    float e = __expf(acc[i][jj][r] * scale);
                    cs[jj] += e;
                    o[r] = (bf16)e;
                }
                *(bf16x4*)&((bf16*)Cv)[(size_t)bz * cb + (size_t)col * ldc + row] = o;
            }
#pragma unroll
        for (int jj = 0; jj < 4; jj++) {
            cs[jj] += __shfl_xor(cs[jj], 16, 64);
            cs[jj] += __shfl_xor(cs[jj], 32, 64);
        }
        if (q == 0) {
#pragma unroll
            for (int jj = 0; jj < 4; jj++)
                atomicAdd(&rowsum[(size_t)bz * SS + n0 + wn + jj * 16 + cl], cs[jj]);
        }
        return;
    }

    const bool v_block = (EPI == 3) && (n0 >= 1024);
#pragma unroll
    for (int i = 0; i < 8; i++) {
#pragma unroll
        for (int jj = 0; jj < 4; jj++) {
            int col = n0 + wn + jj * 16 + cl;
            float bvv = bias ? bias[col] : 0.0f;
            if (v_block) {
                int row = m0 + wm + i * 16 + q * 4;
                int b = row >> 11, s = row & 2047;
                bf16x4 o;
#pragma unroll
                for (int r = 0; r < 4; r++) o[r] = (bf16)(acc[i][jj][r] * scale + bvv);
                *(bf16x4*)&vTp[((size_t)b * DD + (col - 1024)) * SS + s] = o;
            } else {
#pragma unroll
                for (int r = 0; r < 4; r++) {
                    int row = m0 + wm + i * 16 + q * 4 + r;
                    float val = acc[i][jj][r] * scale + bvv;
                    if (OUT_BF16)
                        ((bf16*)Cv)[(size_t)bz * cb + (size_t)row * ldc + col] = (bf16)val;
                    else
                        ((float*)Cv)[(size_t)bz * cb + (size_t)row * ldc + col] = val;
                }
            }
        }
    }
}

// ---------------------------------------------------------------------------
// k_pv (R7/R9-proven): ctx^T = vT x expS^T on the old 128x64 2-barrier core.
// A=vT (M=DD rows), B=expS^T (N=SS q-cols), EPI5: /rowsum[col], packed b64
// C^T store -> ctxb[b][q][d] row-major. Grid (SS/64, DD/128, BB) = 512 wgs.
// ---------------------------------------------------------------------------
__global__ __launch_bounds__(256) void k_pv(const bf16* __restrict__ A,
        const bf16* __restrict__ Bm, float* __restrict__ rowsum,
        bf16* __restrict__ Cv, int K, int lda, int ldb, int ldc,
        long ab, long bb, long cb) {
    __shared__ bf16 As[128 * 64];
    __shared__ bf16 Bs[64 * 64];
    int bx, by, bz;
    xcd_swz(bx, by, bz);
    A += (size_t)bz * ab;
    Bm += (size_t)bz * bb;
    const int m0 = by * 128, n0 = bx * 64;
    const int t = threadIdx.x, lane = t & 63, w = t >> 6;
    const int wm = w * 32, wn = 0;
    const int q = lane >> 4, cl = lane & 15;
    const int srow = lane >> 3;
    const int sblk = (lane & 7) ^ srow;
    const int scol = sblk * 8;
    const bf16* pa = A + (size_t)(m0 + w * 32 + srow) * lda + scol;
    const bf16* pb = Bm + (size_t)(n0 + w * 16 + srow) * ldb + scol;
    bf16* lA = As + (w * 32) * 64;
    bf16* lB = Bs + (w * 16) * 64;
    const int rblk0 = (q ^ (cl & 7)) * 8;
    const int rblk1 = ((4 + q) ^ (cl & 7)) * 8;

    f32x4 acc[2][4] = {};
    for (int k0 = 0; k0 < K; k0 += 64) {
#pragma unroll
        for (int n = 0; n < 4; n++)
            gl_lds16(pa + k0 + (size_t)(n * 8) * lda, lA + n * 8 * 64);
#pragma unroll
        for (int n = 0; n < 2; n++)
            gl_lds16(pb + k0 + (size_t)(n * 8) * ldb, lB + n * 8 * 64);
        __syncthreads();
#pragma unroll
        for (int h = 0; h < 2; h++) {
            const int rb = h ? rblk1 : rblk0;
            bf16x8 af[2], bfr[4];
#pragma unroll
            for (int i = 0; i < 2; i++)
                af[i] = *(const bf16x8*)&As[(wm + i * 16 + cl) * 64 + rb];
#pragma unroll
            for (int j = 0; j < 4; j++)
                bfr[j] = *(const bf16x8*)&Bs[(wn + j * 16 + cl) * 64 + rb];
#pragma unroll
            for (int i = 0; i < 2; i++)
#pragma unroll
                for (int j = 0; j < 4; j++)
                    acc[i][j] = __builtin_amdgcn_mfma_f32_16x16x32_bf16(af[i], bfr[j], acc[i][j], 0, 0, 0);
        }
        __syncthreads();
    }

    // EPI5: col = q index; /rowsum[col]; packed C^T store -> ctx row-major
    float inv[4];
#pragma unroll
    for (int j = 0; j < 4; j++)
        inv[j] = 1.0f / rowsum[(size_t)bz * SS + n0 + wn + j * 16 + cl];
#pragma unroll
    for (int i = 0; i < 2; i++)
#pragma unroll
        for (int j = 0; j < 4; j++) {
            int col = n0 + wn + j * 16 + cl;
            int row = m0 + wm + i * 16 + q * 4;
            bf16x4 o;
#pragma unroll
            for (int r = 0; r < 4; r++) o[r] = (bf16)(acc[i][j][r] * inv[j]);
            *(bf16x4*)&Cv[(size_t)bz * cb + (size_t)col * ldc + row] = o;
        }
}

// distinct names so rocprof reports per-role counters
__global__ __launch_bounds__(512, 2) void k_qkv(const bf16* A, const bf16* Bm,
        const float* bias, bf16* vTp, void* Cv, int K, int lda, int ldb, int ldc,
        float scale) {
    gemm256_body<true, 3>(A, Bm, bias, nullptr, vTp, Cv, K, lda, ldb, ldc, 0, 0, 0, scale);
}
__global__ __launch_bounds__(512, 2) void k_score(const bf16* A, const bf16* Bm,
        float* rowsum, void* Cv, int K, int lda, int ldb, int ldc,
        long ab, long bb, long cb, float scale) {
    gemm256_body<true, 4>(A, Bm, nullptr, rowsum, nullptr, Cv, K, lda, ldb, ldc, ab, bb, cb, scale);
}
__global__ __launch_bounds__(512, 2) void k_out(const bf16* A, const bf16* Bm,
        const float* bias, void* Cv, int K, int lda, int ldb, int ldc,
        float scale) {
    gemm256_body<false, 0>(A, Bm, bias, nullptr, nullptr, Cv, K, lda, ldb, ldc, 0, 0, 0, scale);
}

// ---------------------------------------------------------------------------
extern "C" void kernel_launch(void* const* d_in, const int* in_sizes, int n_in,
                              void* d_out, int out_size, void* d_ws, size_t ws_size,
                              hipStream_t stream) {
    const float* x    = (const float*)d_in[0];  // (4,2048,2048)
    const float* Wqkv = (const float*)d_in[1];  // (1536,2048)
    const float* bqkv = (const float*)d_in[2];  // (1536,)
    const float* Wo   = (const float*)d_in[3];  // (2048,512)
    const float* bo   = (const float*)d_in[4];  // (2048,)
    float* out = (float*)d_out;                 // (4,2048,2048) fp32

    char* ws = (char*)d_ws;
    size_t off = 0;
    bf16* xb    = (bf16*)(ws + off); off += (size_t)MM * CC * 2;       // 32 MB
    bf16* wqkvb = (bf16*)(ws + off); off += (size_t)ND3 * CC * 2;      // 6 MB
    bf16* wob   = (bf16*)(ws + off); off += (size_t)CC * DD * 2;       // 2 MB
    bf16* qkvb  = (bf16*)(ws + off); off += (size_t)MM * ND3 * 2;      // 24 MB
    bf16* vT    = (bf16*)(ws + off); off += (size_t)BB * DD * SS * 2;  // 8 MB
    bf16* expS  = (bf16*)(ws + off); off += (size_t)BB * SS * SS * 2;  // 32 MB
    bf16* ctxb  = (bf16*)(ws + off); off += (size_t)MM * DD * 2;       // 8 MB
    float* rsum = (float*)(ws + off); off += (size_t)MM * 4;           // 32 KB

    // allow 128 KiB dynamic LDS on the ring-pipelined kernels
    static int lds_attr_set = 0;
    if (!lds_attr_set) {
        hipFuncSetAttribute((const void*)k_qkv,
                            hipFuncAttributeMaxDynamicSharedMemorySize, 131072);
        hipFuncSetAttribute((const void*)k_score,
                            hipFuncAttributeMaxDynamicSharedMemorySize, 131072);
        hipFuncSetAttribute((const void*)k_out,
                            hipFuncAttributeMaxDynamicSharedMemorySize, 131072);
        lds_attr_set = 1;
    }

    // 1. convert inputs to bf16 + zero rsum
    prep<<<2048, 256, 0, stream>>>(x, Wqkv, Wo, xb, wqkvb, wob, rsum);

    // 2. qkv = x Wqkv^T + bqkv; q,k -> qkvb rows, v -> vT transposed
    k_qkv<<<dim3(ND3 / 256, MM / 256, 1), 512, 131072, stream>>>(
        xb, wqkvb, bqkv, vT, qkvb, CC, CC, CC, ND3, 1.0f);

    // 3. expS = exp(q k^T / sqrt(d)) via S^T = k q^T; packed C^T store gives
    //    expS[q][k] row-major; col-sum atomics -> rsum[q]
    k_score<<<dim3(SS / 256, SS / 256, BB), 512, 131072, stream>>>(
        qkvb + 512 /*k*/, qkvb /*q*/, rsum, expS,
        DD, ND3, ND3, SS,
        (long)SS * ND3, (long)SS * ND3, (long)SS * SS,
        0.044194173824159216f /* 1/sqrt(512) */);

    // 4. ctx[q][d] via ctx^T = vT expS^T; /rowsum[col]; packed stores
    k_pv<<<dim3(SS / 64, DD / 128, BB), 256, 0, stream>>>(
        vT, expS, rsum, ctxb,
        SS, SS, SS, DD,
        (long)DD * SS, (long)SS * SS, (long)SS * DD);

    // 5. out = ctx Wo^T + bo  (M=8192, N=2048, K=512) -> fp32
    k_out<<<dim3(CC / 256, MM / 256, 1), 512, 131072, stream>>>(
        ctxb, wob, bo, out, DD, DD, DD, CC, 1.0f);

    (void)in_sizes; (void)n_in; (void)out_size; (void)ws_size;
}